// Round 7
// baseline (100.920 us; speedup 1.0000x reference)
//
#include <hip/hip_runtime.h>

#define SEQ   3456
#define DH    32
#define FPT   216
#define NT    16
#define IMG0  20
#define SCALE 0.17677669529663687f

#define KPAD   40    // Ks row stride (u16): 80 B -> 2-way bank alias (free)
#define VPAD   168   // Vt row stride (u16): 336 B
#define PPITCH 40    // P row stride (u16): 80 B

typedef __attribute__((ext_vector_type(8))) short bf16x8;
typedef __attribute__((ext_vector_type(4))) float f32x4;

#define MFMA16(a,b,c) __builtin_amdgcn_mfma_f32_16x16x32_bf16(a,b,c,0,0,0)

__device__ __forceinline__ unsigned short bfh(float f) {      // fp32->bf16 RTNE
    unsigned u = __float_as_uint(f);
    u += 0x7FFFu + ((u >> 16) & 1u);
    return (unsigned short)(u >> 16);
}
__device__ __forceinline__ float bff(unsigned short h) {
    return __uint_as_float((unsigned)h << 16);
}
__device__ __forceinline__ void split8(const float* f, bf16x8& hi, bf16x8& lo) {
    #pragma unroll
    for (int j = 0; j < 8; ++j) {
        unsigned short h = bfh(f[j]);
        hi[j] = (short)h;
        lo[j] = (short)bfh(f[j] - bff(h));
    }
}

// Precomputed 32-bit key-visibility windows over the 160-key sequence
// (g = d*20+jj): normal queries see d==0 all, d>0 jj!=4; joint queries
// (4<=qm<20) see d==0 all, d>0 jj<4. Truncated at nkeys at runtime.
__constant__ unsigned MN_TAB[5] = {0xFEFFFFFFu, 0xFFFFEFFFu, 0xFFEFFFFEu,
                                   0xEFFFFEFFu, 0xFFFEFFFFu};
__constant__ unsigned MJ_TAB[5] = {0x00FFFFFFu, 0xF0000F00u, 0x000F0000u,
                                   0x0F0000F0u, 0x0000F000u};

// Layouts (m89/m118/m120-verified):
//  A-frag 16x16x32: A[m = lane&15][k = (lane>>4)*8 + j]
//  B-frag:          B[k = (lane>>4)*8 + j][n = lane&15]
//  C/D:             D[row = (lane>>4)*4 + reg][col = lane&15]
// Accuracy: QK = qhi*khi + qlo*khi (k_lo dropped: adds ~1e-3 score noise).
// PV/l hi-only: P rounding cancels in softmax ratio; V rounding ~0.4% rel.
__global__ __launch_bounds__(256)
void eye_attn_mfma3(const float* __restrict__ q, const float* __restrict__ k,
                    const float* __restrict__ v, float* __restrict__ out) {
    __shared__ __align__(16) unsigned short KsHi[160 * KPAD];    // 12.8 KB
    __shared__ __align__(16) unsigned short VtHi[DH * VPAD];     // 10.5 KB
    __shared__ __align__(16) unsigned short Pu[8 * 16 * PPITCH]; // 10.0 KB

    const int t = blockIdx.x, bh = blockIdx.y, half = blockIdx.z;
    const int tid = threadIdx.x;
    const size_t base = (size_t)bh * SEQ * DH;
    const int dmax = (t < 7) ? t : 7;
    const int nkeys = IMG0 * (dmax + 1);     // staged small keys (g = d*20+jj)

    // ---- stage small K rows (bf16 hi) and V^T (bf16 hi), zero-padded ----
    for (int i = tid; i < 160 * 8; i += 256) {
        const int g = i >> 3, c = i & 7;
        float4 kk = make_float4(0.f,0.f,0.f,0.f), vv = make_float4(0.f,0.f,0.f,0.f);
        if (g < nkeys) {
            const int d = g / IMG0, jj = g - d * IMG0;
            const size_t row = base + (size_t)((t - d) * FPT + jj) * DH + c * 4;
            kk = *(const float4*)(k + row);
            vv = *(const float4*)(v + row);
        }
        const float kf[4] = {kk.x, kk.y, kk.z, kk.w};
        const float vf[4] = {vv.x, vv.y, vv.z, vv.w};
        ushort4 khi;
        unsigned short* ah = (unsigned short*)&khi;
        #pragma unroll
        for (int e = 0; e < 4; ++e) ah[e] = bfh(kf[e]);
        *(ushort4*)(KsHi + g * KPAD + c * 4) = khi;
        #pragma unroll
        for (int e = 0; e < 4; ++e)
            VtHi[(c * 4 + e) * VPAD + g] = bfh(vf[e]);
    }
    __syncthreads();   // only barrier; Pu regions are wave-private below

    const int wv = tid >> 6, lane = tid & 63;
    const int col = lane & 15, quad = lane >> 4;

    // runtime-truncated visibility masks (wave-uniform)
    unsigned mNt[5], mJt[5];
    #pragma unroll
    for (int kt = 0; kt < 5; ++kt) {
        const int tr = nkeys - kt * 32;
        unsigned mn = MN_TAB[kt], mj = MJ_TAB[kt];
        if (tr <= 0) { mn = 0u; mj = 0u; }
        else if (tr < 32) { const unsigned lim = (1u << tr) - 1u; mn &= lim; mj &= lim; }
        mNt[kt] = mn; mJt[kt] = mj;
    }

    // 14 M-tiles over 2 WGs x 4 waves; img work (tiles 0,1) on half0 w0/w1
    int mt[2]; int mcnt; bool do_img = false;
    if (half == 0) {
        if (wv == 0)      { mt[0] = 0; mcnt = 1; do_img = true; }
        else if (wv == 1) { mt[0] = 1; mcnt = 1; do_img = true; }
        else if (wv == 2) { mt[0] = 2; mt[1] = 3; mcnt = 2; }
        else              { mt[0] = 4; mt[1] = 5; mcnt = 2; }
    } else {
        mt[0] = 6 + 2 * wv; mt[1] = 7 + 2 * wv; mcnt = 2;
    }

    bf16x8 bones;   // B[k][0] = 1: row-sum via MFMA -> l lands in col 0
    #pragma unroll
    for (int j = 0; j < 8; ++j) bones[j] = (short)(col == 0 ? 0x3F80 : 0);

    for (int mi = 0; mi < mcnt; ++mi) {
        const int mb = mt[mi] * 16;
        bf16x8 qhi, qlo;
        {
            const int qc = min(mb + col, FPT - 1);   // clamp; masked via vis
            const float* qp = q + base + (size_t)(t * FPT + qc) * DH + quad * 8;
            float qf[8];
            const float4 a0 = *(const float4*)qp;
            const float4 a1 = *(const float4*)(qp + 4);
            qf[0]=a0.x*SCALE; qf[1]=a0.y*SCALE; qf[2]=a0.z*SCALE; qf[3]=a0.w*SCALE;
            qf[4]=a1.x*SCALE; qf[5]=a1.y*SCALE; qf[6]=a1.z*SCALE; qf[7]=a1.w*SCALE;
            split8(qf, qhi, qlo);
        }
        f32x4 oacc0 = {0.f,0.f,0.f,0.f}, oacc1 = {0.f,0.f,0.f,0.f};
        f32x4 lacc = {0.f,0.f,0.f,0.f};

        // ---- small keys: fixed 5 kt-units, fully unrolled, P dbuf ----
        #pragma unroll
        for (int kt = 0; kt < 5; ++kt) {
            unsigned short* myP = Pu + (wv * 2 + (kt & 1)) * 16 * PPITCH;
            f32x4 s[2];
            #pragma unroll
            for (int h = 0; h < 2; ++h) {
                const int key = kt * 32 + h * 16 + col;
                const bf16x8 khi = *(const bf16x8*)(KsHi + key * KPAD + quad * 8);
                f32x4 acc = {0.f,0.f,0.f,0.f};
                acc = MFMA16(qhi, khi, acc);
                acc = MFMA16(qlo, khi, acc);
                s[h] = acc;
            }
            #pragma unroll
            for (int r = 0; r < 4; ++r) {
                const int qm = mb + quad * 4 + r;
                const bool isj = (qm >= 4) && (qm < IMG0);
                const unsigned m = (qm < FPT) ? (isj ? mJt[kt] : mNt[kt]) : 0u;
                #pragma unroll
                for (int h = 0; h < 2; ++h) {
                    const float e = ((m >> (h * 16 + col)) & 1u)
                                    ? __expf(s[h][r]) : 0.f;
                    myP[(quad * 4 + r) * PPITCH + h * 16 + col] = bfh(e);
                }
            }
            const bf16x8 phi = *(const bf16x8*)(myP + col * PPITCH + quad * 8);
            #pragma unroll
            for (int h = 0; h < 2; ++h) {
                const int dim = h * 16 + col;
                const bf16x8 vhi = *(const bf16x8*)(VtHi + dim * VPAD + kt * 32 + quad * 8);
                f32x4& oa = h ? oacc1 : oacc0;
                oa = MFMA16(phi, vhi, oa);
            }
            lacc = MFMA16(phi, bones, lacc);
        }

        // ---- same-t img keys (20..215): only queries qm<20 (tiles 0,1) ----
        if (mi == 0 && do_img) {
            for (int kt2 = 0; kt2 < 7; ++kt2) {
                unsigned short* myP = Pu + (wv * 2 + (kt2 & 1)) * 16 * PPITCH;
                f32x4 s[2];
                #pragma unroll
                for (int h = 0; h < 2; ++h) {
                    const int keyc = min(IMG0 + kt2 * 32 + h * 16 + col, FPT - 1);
                    const float* kp = k + base + (size_t)(t * FPT + keyc) * DH + quad * 8;
                    float kf[8];
                    const float4 a0 = *(const float4*)kp;
                    const float4 a1 = *(const float4*)(kp + 4);
                    kf[0]=a0.x; kf[1]=a0.y; kf[2]=a0.z; kf[3]=a0.w;
                    kf[4]=a1.x; kf[5]=a1.y; kf[6]=a1.z; kf[7]=a1.w;
                    bf16x8 khi;
                    #pragma unroll
                    for (int j = 0; j < 8; ++j) khi[j] = (short)bfh(kf[j]);
                    f32x4 acc = {0.f,0.f,0.f,0.f};
                    acc = MFMA16(qhi, khi, acc);
                    acc = MFMA16(qlo, khi, acc);
                    s[h] = acc;
                }
                #pragma unroll
                for (int h = 0; h < 2; ++h) {
                    const int key = IMG0 + kt2 * 32 + h * 16 + col;
                    #pragma unroll
                    for (int r = 0; r < 4; ++r) {
                        const int qm = mb + quad * 4 + r;
                        const bool vis = (key < FPT) && (qm < IMG0);
                        const float e = vis ? __expf(s[h][r]) : 0.f;
                        myP[(quad * 4 + r) * PPITCH + h * 16 + col] = bfh(e);
                    }
                }
                const bf16x8 phi = *(const bf16x8*)(myP + col * PPITCH + quad * 8);
                #pragma unroll
                for (int h = 0; h < 2; ++h) {
                    const int dim = h * 16 + col;
                    float vf[8];
                    #pragma unroll
                    for (int j = 0; j < 8; ++j) {
                        const int ky = min(IMG0 + kt2 * 32 + quad * 8 + j, FPT - 1);
                        vf[j] = v[base + (size_t)(t * FPT + ky) * DH + dim];
                    }
                    bf16x8 vhi;
                    #pragma unroll
                    for (int j = 0; j < 8; ++j) vhi[j] = (short)bfh(vf[j]);
                    f32x4& oa = h ? oacc1 : oacc0;
                    oa = MFMA16(phi, vhi, oa);
                }
                lacc = MFMA16(phi, bones, lacc);
            }
        }

        // ---- epilogue: broadcast l (col 0 of quad), normalize, store ----
        #pragma unroll
        for (int r = 0; r < 4; ++r) {
            const float lr = __shfl(lacc[r], lane & 48);   // lane (quad*16 + 0)
            const float inv = 1.f / lr;
            const int qm = mb + quad * 4 + r;
            if (qm < FPT) {
                float* op = out + base + (size_t)(t * FPT + qm) * DH;
                op[col]      = oacc0[r] * inv;
                op[16 + col] = oacc1[r] * inv;
            }
        }
    }
}

extern "C" void kernel_launch(void* const* d_in, const int* in_sizes, int n_in,
                              void* d_out, int out_size, void* d_ws, size_t ws_size,
                              hipStream_t stream) {
    const float* q = (const float*)d_in[0];
    const float* k = (const float*)d_in[1];
    const float* v = (const float*)d_in[2];
    float* out = (float*)d_out;
    const int BH = in_sizes[0] / (SEQ * DH);   // 24
    dim3 grid(NT, BH, 2);                      // 768 WGs = 3/CU even
    eye_attn_mfma3<<<grid, 256, 0, stream>>>(q, k, v, out);
}